// Round 9
// baseline (152.217 us; speedup 1.0000x reference)
//
#include <hip/hip_runtime.h>
#include <hip/hip_bf16.h>

// BCNet fused pipeline, MI355X gfx950 — round 9: 128² ring-4 half-K pipeline.
// 64 KB LDS -> 2 blocks/CU, grid 576 (full fill + cross-block TLP), 1 phase per
// 32-K unit: MFMA 16 | tail-read next frags | stage unit u+4 | vmcnt(8) | bar.
// Pair-packed LDS layout (row r -> lds-row r>>1, half r&1) gives 3 swizzle bits
// at 128B lds-rows: byte ^= ((r>>1)&7)<<4 -> conflict-free b128 reads.
//   C0: convert v,q,Wv,Wq,W2 f32 -> bf16 (one kernel)
//   K1: q_[1792,2048]   = relu(qb @ Wqb^T + bq)
//   K2: qw[128,2048]    = sum_q q_[b*14+q,:] * wh[q]
//   K3: logits[4608,2048] = relu(vb @ Wvb^T + bv) * qw[b,:] + bh
//   K4: out[4608,2048]  = logits @ W2b^T + b2

typedef __attribute__((ext_vector_type(4))) float f32x4;
typedef __attribute__((ext_vector_type(8))) short short8;

__device__ __forceinline__ short f2bf(float f) {
    union { float f; unsigned u; } x; x.f = f;
    unsigned u = x.u;
    unsigned r = (u + 0x7FFFu + ((u >> 16) & 1u)) >> 16;   // RN-even
    return (short)(r & 0xFFFFu);
}
__device__ __forceinline__ float bf2f(short s) {
    union { unsigned u; float f; } x; x.u = ((unsigned)(unsigned short)s) << 16;
    return x.f;
}

__device__ __forceinline__ void gload_lds16(const short* g, short* l) {
    __builtin_amdgcn_global_load_lds(
        (const __attribute__((address_space(1))) unsigned int*)g,
        (__attribute__((address_space(3))) unsigned int*)l,
        16, 0, 0);
}

// ---------------- merged f32 -> bf16 conversion (5 tensors, 1 launch) ----------------
#define CV0 1179648
#define CV1 1703936   // +Wv
#define CV2 2228224   // +W2
#define CV3 2457600   // +q
#define CV4 2719744   // +Wq (total)
__global__ __launch_bounds__(256)
void cvt_all(const float* __restrict__ v,  short* __restrict__ vb,
             const float* __restrict__ Wv, short* __restrict__ Wvb,
             const float* __restrict__ W2, short* __restrict__ W2b,
             const float* __restrict__ q,  short* __restrict__ qb,
             const float* __restrict__ Wq, short* __restrict__ Wqb)
{
    const int stride = gridDim.x * 256;
    for (int c = blockIdx.x * 256 + threadIdx.x; c < CV4; c += stride) {
        const float* src; short* dst; int i;
        if      (c < CV0) { src = v;  dst = vb;  i = c * 8; }
        else if (c < CV1) { src = Wv; dst = Wvb; i = (c - CV0) * 8; }
        else if (c < CV2) { src = W2; dst = W2b; i = (c - CV1) * 8; }
        else if (c < CV3) { src = q;  dst = qb;  i = (c - CV2) * 8; }
        else              { src = Wq; dst = Wqb; i = (c - CV3) * 8; }
        f32x4 a = *(const f32x4*)&src[i];
        f32x4 b = *(const f32x4*)&src[i + 4];
        short8 s;
        #pragma unroll
        for (int j = 0; j < 4; ++j) { s[j] = f2bf(a[j]); s[4 + j] = f2bf(b[j]); }
        *(short8*)&dst[i] = s;
    }
}

// ---------------- 128² ring-4 pipelined GEMM ----------------
// C[M,N] = A[M,K] * B[N,K]^T, bf16 row-major, K % 64 == 0 (>= 128).
// EPI: 0 = relu(acc+bias[n])                      -> bf16
//      1 = relu(acc+bias[n]) * qw[row/36, n] + bh -> bf16
//      2 = acc + bias[n]                          -> f32
// Unit u = K-slice [u*32, u*32+32) of both A and B tiles (8 KB each).
// Ring of 4 unit-slots (slot = u & 3) per matrix; 64 KB total -> 2 blocks/CU.
// Phase u: MFMA(frags_u); read frags_{u+1} (slot (u+1)&3); stage unit u+4
// into slot u&3; s_waitcnt vmcnt(8) (burst u+2, issued 2 phases ago, arrives);
// s_barrier. Pair-packed LDS: global row r -> lds-row r>>1, byte-in-row
// ((r&1)*64 + k8*16) ^ (((r>>1)&7)<<4).  Stage = linear LDS dest (gload_lds)
// + inverse-swizzled per-lane global source (same involution).
template<int EPI>
__global__ __launch_bounds__(256)
void gemm_r4(const short* __restrict__ Ab, const short* __restrict__ Bb,
             const float* __restrict__ bias, const float* __restrict__ qw,
             const float* __restrict__ bh_p, void* __restrict__ Cp,
             int M, int N, int K)
{
    __shared__ short lds[4][2][64 * 64];   // [slot][A=0/B=1][lr*64 + c] = 64 KiB

    const int tid  = threadIdx.x;
    const int lane = tid & 63;
    const int wid  = tid >> 6;     // 0..3
    const int wr   = wid >> 1;     // 0..1
    const int wc   = wid & 1;      // 0..1
    const int fr   = lane & 15;
    const int fc   = lane >> 4;    // 0..3 -> k-offset fc*8 shorts

    const int row0 = blockIdx.x * 128;
    const int col0 = blockIdx.y * 128;

    // ---- read-address lane constants ----
    // frag m: global row r = wbase + m*16 + fr ; lr = r>>1 ; lr&7 == fr>>1
    const int rd_inrow = (((lane & 1) * 64 + fc * 16) ^ ((fr >> 1) << 4));
    const int rdA_off  = (wr * 32 + (fr >> 1)) * 128 + rd_inrow;   // bytes; +m*1024
    const int rdB_off  = (wc * 32 + (fr >> 1)) * 128 + rd_inrow;

    // ---- stage lane constants (inverse of the layout map) ----
    // gload i: lds byte = i*4096 + tid*16 ; lr = i*32 + (tid>>3); cbyte=(tid&7)*16
    // c' = cbyte ^ ((lr&7)<<4) ; global row = 2*lr + (c'>>6), k-short = (c'&63)/2
    const int cp    = ((tid & 7) ^ ((tid >> 3) & 7)) * 16;
    const int st_r0 = (tid >> 3) * 2 + (cp >> 6);       // + i*64
    const int st_k  = (cp & 63) >> 1;                    // 0,8,16,24

    f32x4 acc[4][4];
    #pragma unroll
    for (int i = 0; i < 4; ++i)
        #pragma unroll
        for (int j = 0; j < 4; ++j)
            acc[i][j] = (f32x4)0.0f;

    const int NU = K >> 5;         // units (= phases); even, >= 8

    auto stage = [&](int u, int slot) {
        const int kc = u * 32 + st_k;
        const short* gA = &Ab[(size_t)(row0 + st_r0) * K + kc];
        const short* gB = &Bb[(size_t)(col0 + st_r0) * K + kc];
        short* la = &lds[slot][0][0] + wid * 512;
        short* lb = &lds[slot][1][0] + wid * 512;
        gload_lds16(gA,                  la);
        gload_lds16(gA + (size_t)64 * K, la + 2048);
        gload_lds16(gB,                  lb);
        gload_lds16(gB + (size_t)64 * K, lb + 2048);
    };

#define RDAB(SLOT, AA, BB)                                                      \
    {                                                                           \
        const char* baA_ = (const char*)&lds[SLOT][0][0] + rdA_off;             \
        const char* baB_ = (const char*)&lds[SLOT][1][0] + rdB_off;             \
        _Pragma("unroll") for (int m_ = 0; m_ < 4; ++m_)                        \
            AA[m_] = *(const short8*)(baA_ + m_ * 1024);                        \
        _Pragma("unroll") for (int n_ = 0; n_ < 4; ++n_)                        \
            BB[n_] = *(const short8*)(baB_ + n_ * 1024);                        \
    }
#define MFMA16(AA, BB)                                                          \
    _Pragma("unroll") for (int m_ = 0; m_ < 4; ++m_)                            \
      _Pragma("unroll") for (int n_ = 0; n_ < 4; ++n_)                          \
        acc[m_][n_] = __builtin_amdgcn_mfma_f32_16x16x32_bf16(                  \
            AA[m_], BB[n_], acc[m_][n_], 0, 0, 0);

#define BAR()   asm volatile("s_barrier" ::: "memory")
#define PRIO1() __builtin_amdgcn_s_setprio(1)
#define PRIO0() __builtin_amdgcn_s_setprio(0)
#define VM8()   asm volatile("s_waitcnt vmcnt(8)" ::: "memory")
#define VM4()   asm volatile("s_waitcnt vmcnt(4)" ::: "memory")
#define VM0()   asm volatile("s_waitcnt vmcnt(0)" ::: "memory")

    short8 a0[4], b0[4], a1[4], b1[4];

    // prologue: units 0..3 in flight; drain so units 0 AND 1 arrived (VM8 keeps
    // bursts 2,3 = 8 loads in flight); read frags_0.
    stage(0, 0); stage(1, 1); stage(2, 2); stage(3, 3);
    VM8();
    BAR();
    RDAB(0, a0, b0);

    // main phases u = 0 .. NU-5 (two per iteration; NU-4 is even)
    for (int ph = 0; ph < (NU - 4) >> 1; ++ph) {
        const int ue = 2 * ph;
        // phase ue (even): cur F0, read F1 <- unit ue+1
        PRIO1(); MFMA16(a0, b0); PRIO0();
        RDAB((ue + 1) & 3, a1, b1);
        stage(ue + 4, ue & 3);
        VM8(); BAR();
        // phase ue+1 (odd): cur F1, read F0 <- unit ue+2
        PRIO1(); MFMA16(a1, b1); PRIO0();
        RDAB((ue + 2) & 3, a0, b0);
        stage(ue + 5, (ue + 1) & 3);
        VM8(); BAR();
    }
    // peeled tail: u = NU-4 .. NU-1 (NU-4 even -> F0 current)
    PRIO1(); MFMA16(a0, b0); PRIO0();          // u = NU-4
    RDAB((NU - 3) & 3, a1, b1);
    VM4(); BAR();
    PRIO1(); MFMA16(a1, b1); PRIO0();          // u = NU-3
    RDAB((NU - 2) & 3, a0, b0);
    VM0(); BAR();
    PRIO1(); MFMA16(a0, b0); PRIO0();          // u = NU-2
    RDAB((NU - 1) & 3, a1, b1);
    BAR();
    PRIO1(); MFMA16(a1, b1); PRIO0();          // u = NU-1

#undef RDAB
#undef MFMA16
#undef BAR
#undef PRIO1
#undef PRIO0
#undef VM8
#undef VM4
#undef VM0

    // epilogue: C/D layout col = lane&15, row = (lane>>4)*4 + reg
    const float bhv = (EPI == 1) ? bh_p[0] : 0.0f;
    #pragma unroll
    for (int mi = 0; mi < 4; ++mi) {
        #pragma unroll
        for (int ni = 0; ni < 4; ++ni) {
            #pragma unroll
            for (int r = 0; r < 4; ++r) {
                const int row = row0 + wr * 64 + mi * 16 + fc * 4 + r;
                const int col = col0 + wc * 64 + ni * 16 + fr;
                float val = acc[mi][ni][r];
                if (EPI == 0) {
                    val = fmaxf(val + bias[col], 0.0f);
                    ((short*)Cp)[(size_t)row * N + col] = f2bf(val);
                } else if (EPI == 1) {
                    val = fmaxf(val + bias[col], 0.0f);
                    const int bb = row / 36;
                    val = val * qw[bb * 2048 + col] + bhv;
                    ((short*)Cp)[(size_t)row * N + col] = f2bf(val);
                } else {
                    ((float*)Cp)[(size_t)row * N + col] = val + bias[col];
                }
            }
        }
    }
}

// qw[b,h] = sum_q bf2f(q_[b*14+q, h]) * wh[q]
__global__ __launch_bounds__(256)
void qw_reduce(const short* __restrict__ q_, const float* __restrict__ wh,
               float* __restrict__ qw)
{
    const int idx = blockIdx.x * 256 + threadIdx.x;
    const int b = idx >> 11;
    const int h = idx & 2047;
    float s = 0.0f;
    #pragma unroll
    for (int qq = 0; qq < 14; ++qq)
        s += bf2f(q_[(size_t)(b * 14 + qq) * 2048 + h]) * wh[qq];
    qw[idx] = s;
}

extern "C" void kernel_launch(void* const* d_in, const int* in_sizes, int n_in,
                              void* d_out, int out_size, void* d_ws, size_t ws_size,
                              hipStream_t stream)
{
    const float* v  = (const float*)d_in[0];
    const float* q  = (const float*)d_in[1];
    const float* Wv = (const float*)d_in[2];
    const float* bv = (const float*)d_in[3];
    const float* Wq = (const float*)d_in[4];
    const float* bq = (const float*)d_in[5];
    const float* wh = (const float*)d_in[6];
    const float* bh = (const float*)d_in[7];
    const float* W2 = (const float*)d_in[8];
    const float* b2 = (const float*)d_in[9];
    float* out = (float*)d_out;

    char* ws = (char*)d_ws;
    short* vb     = (short*)(ws);                  // 4608*2048*2 = 18,874,368
    short* Wvb    = (short*)(ws + 18874368);       // 2048*2048*2 =  8,388,608
    short* W2b    = (short*)(ws + 27262976);       // 2048*2048*2 =  8,388,608
    short* qb     = (short*)(ws + 35651584);       // 1792*1024*2 =  3,670,016
    short* Wqb    = (short*)(ws + 39321600);       // 2048*1024*2 =  4,194,304
    short* q_ws   = (short*)(ws + 43515904);       // 1792*2048*2 =  7,340,032
    float* qw     = (float*)(ws + 50855936);       // 128*2048*4  =  1,048,576
    short* logits = (short*)(ws + 51904512);       // 4608*2048*2 = 18,874,368
    // total: 70,778,880 B

    // C0: all conversions in one launch
    cvt_all<<<2048, 256, 0, stream>>>(v, vb, Wv, Wvb, W2, W2b, q, qb, Wq, Wqb);

    // K1: q_ = relu(qb @ Wqb^T + bq)   M=1792, N=2048, K=1024
    gemm_r4<0><<<dim3(1792 / 128, 2048 / 128), 256, 0, stream>>>(
        qb, Wqb, bq, nullptr, nullptr, q_ws, 1792, 2048, 1024);

    // K2: qw reduce
    qw_reduce<<<(128 * 2048) / 256, 256, 0, stream>>>(q_ws, wh, qw);

    // K3: logits = relu(vb @ Wvb^T + bv) * qw + bh   M=4608, N=2048, K=2048
    gemm_r4<1><<<dim3(4608 / 128, 2048 / 128), 256, 0, stream>>>(
        vb, Wvb, bv, qw, bh, logits, 4608, 2048, 2048);

    // K4: out = logits @ W2b^T + b2   M=4608, N=2048, K=2048
    gemm_r4<2><<<dim3(4608 / 128, 2048 / 128), 256, 0, stream>>>(
        logits, W2b, b2, nullptr, nullptr, out, 4608, 2048, 2048);
}

// Round 10
// 140.654 us; speedup vs baseline: 1.0822x; 1.0822x over previous
//
#include <hip/hip_runtime.h>
#include <hip/hip_bf16.h>

// BCNet fused pipeline, MI355X gfx950 — round 10.
// K3/K4 keep R8's proven 256² 1-barrier rotated 8-phase kernel (57 µs each).
// New: cvt(v,Wv,W2) (pure memory, ~104 MB) fused INTO the K1 GEMM launch as
// extra blocks -> overlaps with K1's compute (whose inputs are L2-resident).
//   C0: cvt_qw    q,Wq f32->bf16                       (~3 µs)
//   K1f: blocks 0-223  : q_ = relu(qb @ Wqb^T + bq)    (128² BK=64 GEMM)
//        blocks 224-511: convert v,Wv,W2 f32->bf16     (overlapped)
//   K2: qw[128,2048] = sum_q q_[b*14+q,:] * wh[q]
//   K3: logits = relu(vb @ Wvb^T + bv) * qw + bh       (256² 8-phase)
//   K4: out = logits @ W2b^T + b2                      (256² 8-phase)

typedef __attribute__((ext_vector_type(4))) float f32x4;
typedef __attribute__((ext_vector_type(8))) short short8;

__device__ __forceinline__ short f2bf(float f) {
    union { float f; unsigned u; } x; x.f = f;
    unsigned u = x.u;
    unsigned r = (u + 0x7FFFu + ((u >> 16) & 1u)) >> 16;   // RN-even
    return (short)(r & 0xFFFFu);
}
__device__ __forceinline__ float bf2f(short s) {
    union { unsigned u; float f; } x; x.u = ((unsigned)(unsigned short)s) << 16;
    return x.f;
}

__device__ __forceinline__ void gload_lds16(const short* g, short* l) {
    __builtin_amdgcn_global_load_lds(
        (const __attribute__((address_space(1))) unsigned int*)g,
        (__attribute__((address_space(3))) unsigned int*)l,
        16, 0, 0);
}

__device__ __forceinline__ void cvt_chunk(const float* __restrict__ src,
                                          short* __restrict__ dst, int i)
{
    f32x4 a = *(const f32x4*)&src[i];
    f32x4 b = *(const f32x4*)&src[i + 4];
    short8 s;
    #pragma unroll
    for (int j = 0; j < 4; ++j) { s[j] = f2bf(a[j]); s[4 + j] = f2bf(b[j]); }
    *(short8*)&dst[i] = s;
}

// ---------------- cvt of q, Wq (must precede K1) ----------------
#define Q_CH  229376                  // 1792*1024/8
#define QW_CH 262144                  // 2048*1024/8
__global__ __launch_bounds__(256)
void cvt_qw(const float* __restrict__ q,  short* __restrict__ qb,
            const float* __restrict__ Wq, short* __restrict__ Wqb)
{
    const int total = Q_CH + QW_CH;
    const int stride = gridDim.x * 256;
    for (int c = blockIdx.x * 256 + threadIdx.x; c < total; c += stride) {
        if (c < Q_CH) cvt_chunk(q, qb, c * 8);
        else          cvt_chunk(Wq, Wqb, (c - Q_CH) * 8);
    }
}

// ---------------- K1 fused: 128² BK=64 GEMM (blocks 0..223) + cvt (224..511) ----------------
// GEMM: q_[1792,2048] = relu(qb[1792,1024] @ Wqb[2048,1024]^T + bq) -> bf16
#define V_CH  1179648                 // 4608*2048/8
#define WV_CH 524288                  // 2048*2048/8
#define W2_CH 524288
__global__ __launch_bounds__(256)
void k1_fused(const short* __restrict__ Ab, const short* __restrict__ Bb,
              const float* __restrict__ bias, short* __restrict__ Cp,
              const float* __restrict__ v,  short* __restrict__ vb,
              const float* __restrict__ Wv, short* __restrict__ Wvb,
              const float* __restrict__ W2, short* __restrict__ W2b)
{
    __shared__ short ldsA[128 * 64];
    __shared__ short ldsB[128 * 64];

    if (blockIdx.x >= 224) {
        // ---- conversion path: v, Wv, W2 ----
        const int total = V_CH + WV_CH + W2_CH;          // 2,228,224 chunks
        const int stride = 288 * 256;
        for (int c = (blockIdx.x - 224) * 256 + threadIdx.x; c < total; c += stride) {
            if      (c < V_CH)         cvt_chunk(v,  vb,  c * 8);
            else if (c < V_CH + WV_CH) cvt_chunk(Wv, Wvb, (c - V_CH) * 8);
            else                       cvt_chunk(W2, W2b, (c - V_CH - WV_CH) * 8);
        }
        return;
    }

    // ---- GEMM path (R6/R8-proven gemm_bt128, M=1792 N=2048 K=1024) ----
    const int K = 1024, N = 2048;
    const int tid    = threadIdx.x;
    const int lane   = tid & 63;
    const int wid    = tid >> 6;
    const int wr     = wid >> 1;
    const int wc     = wid & 1;
    const int lrow   = lane & 15;
    const int lchunk = lane >> 4;

    const int row0 = (blockIdx.x % 14) * 128;
    const int col0 = (blockIdx.x / 14) * 128;

    const int s_r = lane >> 3;
    const int s_c = ((lane & 7) ^ s_r) * 8;

    f32x4 acc[4][4];
    #pragma unroll
    for (int i = 0; i < 4; ++i)
        #pragma unroll
        for (int j = 0; j < 4; ++j)
            acc[i][j] = (f32x4)0.0f;

    const int nk = K >> 6;

    for (int kt = 0; kt < nk; ++kt) {
        const int kc = kt * 64;
        if (kt) __syncthreads();
        #pragma unroll
        for (int i = 0; i < 4; ++i) {
            const int r = wid * 32 + i * 8 + s_r;
            gload_lds16(&Ab[(size_t)(row0 + r) * K + kc + s_c],
                        &ldsA[(wid * 32 + i * 8) * 64]);
            gload_lds16(&Bb[(size_t)(col0 + r) * K + kc + s_c],
                        &ldsB[(wid * 32 + i * 8) * 64]);
        }
        __syncthreads();

        short8 af[4][2], bfv[4][2];
        #pragma unroll
        for (int mi = 0; mi < 4; ++mi) {
            const int row = wr * 64 + mi * 16 + lrow;
            #pragma unroll
            for (int ks = 0; ks < 2; ++ks)
                af[mi][ks] = *(const short8*)((const char*)ldsA +
                    row * 128 + (((ks * 4 + lchunk) * 16) ^ ((row & 7) << 4)));
        }
        #pragma unroll
        for (int ni = 0; ni < 4; ++ni) {
            const int row = wc * 64 + ni * 16 + lrow;
            #pragma unroll
            for (int ks = 0; ks < 2; ++ks)
                bfv[ni][ks] = *(const short8*)((const char*)ldsB +
                    row * 128 + (((ks * 4 + lchunk) * 16) ^ ((row & 7) << 4)));
        }
        #pragma unroll
        for (int ks = 0; ks < 2; ++ks)
            #pragma unroll
            for (int mi = 0; mi < 4; ++mi)
                #pragma unroll
                for (int ni = 0; ni < 4; ++ni)
                    acc[mi][ni] = __builtin_amdgcn_mfma_f32_16x16x32_bf16(
                        af[mi][ks], bfv[ni][ks], acc[mi][ni], 0, 0, 0);
    }

    #pragma unroll
    for (int mi = 0; mi < 4; ++mi)
        #pragma unroll
        for (int ni = 0; ni < 4; ++ni)
            #pragma unroll
            for (int r = 0; r < 4; ++r) {
                const int row = row0 + wr * 64 + mi * 16 + lchunk * 4 + r;
                const int col = col0 + wc * 64 + ni * 16 + lrow;
                float val = fmaxf(acc[mi][ni][r] + bias[col], 0.0f);
                Cp[(size_t)row * N + col] = f2bf(val);
            }
}

// ---------------- 256² 8-phase pipelined GEMM, rotated phases (K3/K4) — R8 proven ----------------
template<int EPI>
__global__ __launch_bounds__(512, 2)
void gemm256(const short* __restrict__ Ab, const short* __restrict__ Bb,
             const float* __restrict__ bias, const float* __restrict__ qw,
             const float* __restrict__ bh_p, void* __restrict__ Cp,
             int M, int N, int K)
{
    __shared__ short lds[2][4][128 * 64];   // [buf][Aq0,Aq1,Bq0,Bq1] = 128 KiB

    const int tid  = threadIdx.x;
    const int lane = tid & 63;
    const int w    = tid >> 6;     // 0..7
    const int wr   = w >> 2;       // 0..1
    const int wc   = w & 3;        // 0..3
    const int fr   = lane & 15;
    const int fc   = lane >> 4;

    const int row0 = blockIdx.x * 256;
    const int col0 = blockIdx.y * 256;

    const int sl_s = lane >> 3;                    // 0..7
    const int sl_c = ((lane & 7) ^ sl_s) * 8;      // pre-swizzled source col (shorts)

    const int nt = K >> 6;         // even, >= 4

    f32x4 acc[8][4];
    #pragma unroll
    for (int i = 0; i < 8; ++i)
        #pragma unroll
        for (int j = 0; j < 4; ++j)
            acc[i][j] = (f32x4)0.0f;

    auto stageA = [&](int t, int q) {
        #pragma unroll
        for (int i = 0; i < 2; ++i) {
            const int g  = w * 2 + i;                  // 0..15
            const int rl = g * 8 + sl_s;               // 0..127 unit row
            const int srow = row0 + (g >> 3) * 128 + q * 64 + (rl & 63);
            gload_lds16(&Ab[(size_t)srow * K + t * 64 + sl_c],
                        &lds[t & 1][q][g * 512]);
        }
    };
    auto stageB = [&](int t, int q) {
        #pragma unroll
        for (int i = 0; i < 2; ++i) {
            const int g  = w * 2 + i;
            const int rl = g * 8 + sl_s;
            const int srow = col0 + (rl >> 5) * 64 + q * 32 + (rl & 31);
            gload_lds16(&Bb[(size_t)srow * K + t * 64 + sl_c],
                        &lds[t & 1][2 + q][g * 512]);
        }
    };

    short8 A0[4][2], A1[4][2], B0[2][2], B1[2][2];

#define READA(T, MQ, DST)                                                       \
    _Pragma("unroll") for (int m_ = 0; m_ < 4; ++m_) {                          \
        const int rl_ = wr * 64 + m_ * 16 + fr;                                 \
        _Pragma("unroll") for (int k_ = 0; k_ < 2; ++k_)                        \
            DST[m_][k_] = *(const short8*)((const char*)&lds[(T) & 1][MQ][0]    \
                + rl_ * 128 + ((k_ * 64 + fc * 16) ^ ((rl_ & 7) << 4)));        \
    }
#define READB(T, NQ, DST)                                                       \
    _Pragma("unroll") for (int n_ = 0; n_ < 2; ++n_) {                          \
        const int rl_ = wc * 32 + n_ * 16 + fr;                                 \
        _Pragma("unroll") for (int k_ = 0; k_ < 2; ++k_)                        \
            DST[n_][k_] = *(const short8*)((const char*)&lds[(T) & 1][2 + (NQ)][0] \
                + rl_ * 128 + ((k_ * 64 + fc * 16) ^ ((rl_ & 7) << 4)));        \
    }
#define MFMAQ(MQ, NQ, ASET, BSET)                                               \
    _Pragma("unroll") for (int m_ = 0; m_ < 4; ++m_)                            \
      _Pragma("unroll") for (int n_ = 0; n_ < 2; ++n_)                          \
        _Pragma("unroll") for (int k_ = 0; k_ < 2; ++k_)                        \
          acc[(MQ) * 4 + m_][(NQ) * 2 + n_] =                                   \
              __builtin_amdgcn_mfma_f32_16x16x32_bf16(                          \
                  ASET[m_][k_], BSET[n_][k_], acc[(MQ) * 4 + m_][(NQ) * 2 + n_], 0, 0, 0);

#define BAR()   asm volatile("s_barrier" ::: "memory")
#define PRIO1() __builtin_amdgcn_s_setprio(1)
#define PRIO0() __builtin_amdgcn_s_setprio(0)
#define VM4()   asm volatile("s_waitcnt vmcnt(4)" ::: "memory")
#define VM0()   asm volatile("s_waitcnt vmcnt(0)" ::: "memory")

#define KITER(T0, T1, ST1, ST2, ST3, ST4, ST5, ST6, ST7, ST8, D4, D8)           \
  {                                                                             \
    READA(T0, 0, A0); READB(T0, 0, B0);                                         \
    PRIO1(); MFMAQ(0, 0, A0, B0); PRIO0();                                      \
    READB(T0, 1, B1); ST1; BAR();                                               \
    PRIO1(); MFMAQ(0, 1, A0, B1); PRIO0();                                      \
    READA(T0, 1, A1); ST2; BAR();                                               \
    PRIO1(); MFMAQ(1, 1, A1, B1); PRIO0();                                      \
    ST3; BAR();                                                                 \
    PRIO1(); MFMAQ(1, 0, A1, B0); PRIO0();                                      \
    ST4; D4; BAR();                                                             \
    READA(T1, 0, A0); READB(T1, 0, B0);                                         \
    PRIO1(); MFMAQ(0, 0, A0, B0); PRIO0();                                      \
    READB(T1, 1, B1); ST5; BAR();                                               \
    PRIO1(); MFMAQ(0, 1, A0, B1); PRIO0();                                      \
    READA(T1, 1, A1); ST6; BAR();                                               \
    PRIO1(); MFMAQ(1, 1, A1, B1); PRIO0();                                      \
    ST7; BAR();                                                                 \
    PRIO1(); MFMAQ(1, 0, A1, B0); PRIO0();                                      \
    ST8; D8; BAR();                                                             \
  }

    // prologue: T0 fully + Aq0(T1) + Bq1(T1); drain to T0-complete
    stageA(0, 0); stageB(0, 0); stageB(0, 1); stageA(0, 1);
    stageA(1, 0); stageB(1, 1);
    VM4();
    BAR();

    const int niter = (nt >> 1) - 1;
    for (int j = 0; j < niter; ++j) {
        const int t0 = 2 * j, t1 = 2 * j + 1;
        KITER(t0, t1,
              stageA(t1, 1),     stageB(t1, 0),
              stageA(t0 + 2, 0), stageB(t0 + 2, 1),
              stageA(t0 + 2, 1), stageB(t0 + 2, 0),
              stageA(t1 + 2, 0), stageB(t1 + 2, 1),
              VM4(), VM4());
    }
    // tail iteration
    {
        const int t0 = nt - 2, t1 = nt - 1;
        KITER(t0, t1,
              stageA(t1, 1), stageB(t1, 0),
              (void)0, (void)0, (void)0, (void)0, (void)0, (void)0,
              VM0(), (void)0);
    }

#undef KITER
#undef READA
#undef READB
#undef MFMAQ
#undef BAR
#undef PRIO1
#undef PRIO0
#undef VM4
#undef VM0

    // epilogue: C/D layout col = lane&15, row = (lane>>4)*4 + reg
    const float bhv = (EPI == 1) ? bh_p[0] : 0.0f;
    #pragma unroll
    for (int m = 0; m < 8; ++m) {
        #pragma unroll
        for (int n = 0; n < 4; ++n) {
            #pragma unroll
            for (int r = 0; r < 4; ++r) {
                const int row = row0 + wr * 128 + m * 16 + fc * 4 + r;
                const int col = col0 + wc * 64 + n * 16 + fr;
                float val = acc[m][n][r];
                if (EPI == 1) {
                    val = fmaxf(val + bias[col], 0.0f);
                    const int b = row / 36;
                    val = val * qw[b * 2048 + col] + bhv;
                    ((short*)Cp)[(size_t)row * N + col] = f2bf(val);
                } else {
                    ((float*)Cp)[(size_t)row * N + col] = val + bias[col];
                }
            }
        }
    }
}

// qw[b,h] = sum_q bf2f(q_[b*14+q, h]) * wh[q]
__global__ __launch_bounds__(256)
void qw_reduce(const short* __restrict__ q_, const float* __restrict__ wh,
               float* __restrict__ qw)
{
    const int idx = blockIdx.x * 256 + threadIdx.x;
    const int b = idx >> 11;
    const int h = idx & 2047;
    float s = 0.0f;
    #pragma unroll
    for (int qq = 0; qq < 14; ++qq)
        s += bf2f(q_[(size_t)(b * 14 + qq) * 2048 + h]) * wh[qq];
    qw[idx] = s;
}

extern "C" void kernel_launch(void* const* d_in, const int* in_sizes, int n_in,
                              void* d_out, int out_size, void* d_ws, size_t ws_size,
                              hipStream_t stream)
{
    const float* v  = (const float*)d_in[0];
    const float* q  = (const float*)d_in[1];
    const float* Wv = (const float*)d_in[2];
    const float* bv = (const float*)d_in[3];
    const float* Wq = (const float*)d_in[4];
    const float* bq = (const float*)d_in[5];
    const float* wh = (const float*)d_in[6];
    const float* bh = (const float*)d_in[7];
    const float* W2 = (const float*)d_in[8];
    const float* b2 = (const float*)d_in[9];
    float* out = (float*)d_out;

    char* ws = (char*)d_ws;
    short* vb     = (short*)(ws);                  // 4608*2048*2 = 18,874,368
    short* Wvb    = (short*)(ws + 18874368);       // 2048*2048*2 =  8,388,608
    short* W2b    = (short*)(ws + 27262976);       // 2048*2048*2 =  8,388,608
    short* qb     = (short*)(ws + 35651584);       // 1792*1024*2 =  3,670,016
    short* Wqb    = (short*)(ws + 39321600);       // 2048*1024*2 =  4,194,304
    short* q_ws   = (short*)(ws + 43515904);       // 1792*2048*2 =  7,340,032
    float* qw     = (float*)(ws + 50855936);       // 128*2048*4  =  1,048,576
    short* logits = (short*)(ws + 51904512);       // 4608*2048*2 = 18,874,368
    // total: 70,778,880 B

    // C0: convert q, Wq (needed by K1)
    cvt_qw<<<1024, 256, 0, stream>>>(q, qb, Wq, Wqb);

    // K1 fused: GEMM (224 blocks) + cvt of v/Wv/W2 (288 blocks)
    k1_fused<<<512, 256, 0, stream>>>(qb, Wqb, bq, q_ws,
                                      v, vb, Wv, Wvb, W2, W2b);

    // K2: qw reduce
    qw_reduce<<<(128 * 2048) / 256, 256, 0, stream>>>(q_ws, wh, qw);

    // K3: logits = relu(vb @ Wvb^T + bv) * qw + bh   M=4608, N=2048, K=2048
    gemm256<1><<<dim3(4608 / 256, 2048 / 256), 512, 0, stream>>>(
        vb, Wvb, bv, qw, bh, logits, 4608, 2048, 2048);

    // K4: out = logits @ W2b^T + b2   M=4608, N=2048, K=2048
    gemm256<2><<<dim3(4608 / 256, 2048 / 256), 512, 0, stream>>>(
        logits, W2b, b2, nullptr, nullptr, out, 4608, 2048, 2048);
}